// Round 1
// baseline (10952.637 us; speedup 1.0000x reference)
//
#include <hip/hip_runtime.h>

#define N_USERS   100000
#define N_ITEMS   50000
#define N_NODES   150000
#define EMBED_DIM 64
#define COVER_DIM 512
#define N_EDGES   4000000
#define N_LAYERS  3

// ---------------------------------------------------------------------------
// Build x for user rows: x[0:N_USERS] = user_emb ; also init acc = x
// float4-vectorized copy.
// ---------------------------------------------------------------------------
__global__ void build_user_x(const float* __restrict__ user_emb,
                             float* __restrict__ x,
                             float* __restrict__ acc) {
    int i = blockIdx.x * blockDim.x + threadIdx.x;  // float4 index
    const int n4 = N_USERS * EMBED_DIM / 4;
    if (i < n4) {
        float4 v = reinterpret_cast<const float4*>(user_emb)[i];
        reinterpret_cast<float4*>(x)[i]   = v;
        reinterpret_cast<float4*>(acc)[i] = v;
    }
}

// ---------------------------------------------------------------------------
// Build x for item rows: x = item_emb + has_cover * (item_cover @ W^T)
// 16 threads per item; each thread computes 4 output dims (one float4).
// W is [EMBED_DIM][COVER_DIM] row-major (torch Linear weight), so
// proj[i][d] = sum_k item_cover[i][k] * W[d][k].
// ---------------------------------------------------------------------------
__global__ void build_item_x(const float* __restrict__ item_emb,
                             const float* __restrict__ cover_W,
                             const float* __restrict__ item_cover,
                             const float* __restrict__ has_cover,
                             float* __restrict__ x_items,
                             float* __restrict__ acc_items) {
    int t = blockIdx.x * blockDim.x + threadIdx.x;
    int item = t >> 4;
    int d4   = t & 15;           // which float4 of the 64-dim output
    if (item >= N_ITEMS) return;

    float hc = has_cover[item];
    const float4* ic = reinterpret_cast<const float4*>(item_cover + (size_t)item * COVER_DIM);
    const float4* w0 = reinterpret_cast<const float4*>(cover_W + (size_t)(d4 * 4 + 0) * COVER_DIM);
    const float4* w1 = reinterpret_cast<const float4*>(cover_W + (size_t)(d4 * 4 + 1) * COVER_DIM);
    const float4* w2 = reinterpret_cast<const float4*>(cover_W + (size_t)(d4 * 4 + 2) * COVER_DIM);
    const float4* w3 = reinterpret_cast<const float4*>(cover_W + (size_t)(d4 * 4 + 3) * COVER_DIM);

    float a0 = 0.f, a1 = 0.f, a2 = 0.f, a3 = 0.f;
#pragma unroll 4
    for (int k = 0; k < COVER_DIM / 4; ++k) {
        float4 c  = ic[k];
        float4 u0 = w0[k];
        float4 u1 = w1[k];
        float4 u2 = w2[k];
        float4 u3 = w3[k];
        a0 += c.x * u0.x + c.y * u0.y + c.z * u0.z + c.w * u0.w;
        a1 += c.x * u1.x + c.y * u1.y + c.z * u1.z + c.w * u1.w;
        a2 += c.x * u2.x + c.y * u2.y + c.z * u2.z + c.w * u2.w;
        a3 += c.x * u3.x + c.y * u3.y + c.z * u3.z + c.w * u3.w;
    }

    float4 e = reinterpret_cast<const float4*>(item_emb)[(size_t)item * 16 + d4];
    float4 r;
    r.x = e.x + hc * a0;
    r.y = e.y + hc * a1;
    r.z = e.z + hc * a2;
    r.w = e.w + hc * a3;
    reinterpret_cast<float4*>(x_items)[(size_t)item * 16 + d4]   = r;
    reinterpret_cast<float4*>(acc_items)[(size_t)item * 16 + d4] = r;
}

// ---------------------------------------------------------------------------
// COO SpMM with float atomics: y[rows[e]] += vals[e] * x[cols[e]]
// 16 threads per edge; each handles one float4 (4 dims).
// Groups of 16 lanes read a contiguous 256B segment of x (coalesced).
// ---------------------------------------------------------------------------
__global__ void spmm_atomic(const float* __restrict__ vals,
                            const int* __restrict__ rows,
                            const int* __restrict__ cols,
                            const float* __restrict__ x,
                            float* __restrict__ y) {
    long long t = (long long)blockIdx.x * blockDim.x + threadIdx.x;
    int e    = (int)(t >> 4);
    int part = (int)(t & 15);
    if (e >= N_EDGES) return;

    float v = vals[e];
    int c = cols[e];
    int r = rows[e];

    float4 xa = reinterpret_cast<const float4*>(x)[(size_t)c * 16 + part];
    float* yp = y + (size_t)r * EMBED_DIM + part * 4;
    atomicAdd(yp + 0, v * xa.x);
    atomicAdd(yp + 1, v * xa.y);
    atomicAdd(yp + 2, v * xa.z);
    atomicAdd(yp + 3, v * xa.w);
}

// ---------------------------------------------------------------------------
// acc = (acc + y) * scale   (scale=1 for inner layers, 0.25 for last)
// ---------------------------------------------------------------------------
__global__ void acc_add(float* __restrict__ acc,
                        const float* __restrict__ y,
                        float scale) {
    int i = blockIdx.x * blockDim.x + threadIdx.x;
    const int n4 = N_NODES * EMBED_DIM / 4;
    if (i < n4) {
        float4 a = reinterpret_cast<float4*>(acc)[i];
        float4 b = reinterpret_cast<const float4*>(y)[i];
        a.x = (a.x + b.x) * scale;
        a.y = (a.y + b.y) * scale;
        a.z = (a.z + b.z) * scale;
        a.w = (a.w + b.w) * scale;
        reinterpret_cast<float4*>(acc)[i] = a;
    }
}

extern "C" void kernel_launch(void* const* d_in, const int* in_sizes, int n_in,
                              void* d_out, int out_size, void* d_ws, size_t ws_size,
                              hipStream_t stream) {
    const float* user_emb   = (const float*)d_in[0];
    const float* item_emb   = (const float*)d_in[1];
    const float* cover_W    = (const float*)d_in[2];
    const float* item_cover = (const float*)d_in[3];
    const float* has_cover  = (const float*)d_in[4];
    const float* adj_vals   = (const float*)d_in[5];
    const int*   adj_rows   = (const int*)d_in[6];
    const int*   adj_cols   = (const int*)d_in[7];
    // d_in[8] = n_layers (known fixed = 3 from setup_inputs)

    float* acc = (float*)d_out;                        // [N_NODES][64] running sum
    float* x   = (float*)d_ws;                         // [N_NODES][64]
    float* y   = x + (size_t)N_NODES * EMBED_DIM;      // [N_NODES][64]

    const size_t feat_bytes = (size_t)N_NODES * EMBED_DIM * sizeof(float);

    // x0 = concat(user_emb, item_emb + cover_proj); acc = x0
    {
        int n4 = N_USERS * EMBED_DIM / 4;
        build_user_x<<<(n4 + 255) / 256, 256, 0, stream>>>(user_emb, x, acc);
    }
    {
        int nt = N_ITEMS * 16;
        build_item_x<<<(nt + 255) / 256, 256, 0, stream>>>(
            item_emb, cover_W, item_cover, has_cover,
            x + (size_t)N_USERS * EMBED_DIM,
            acc + (size_t)N_USERS * EMBED_DIM);
    }

    for (int l = 0; l < N_LAYERS; ++l) {
        hipMemsetAsync(y, 0, feat_bytes, stream);
        long long nt = (long long)N_EDGES * 16;
        spmm_atomic<<<(int)((nt + 255) / 256), 256, 0, stream>>>(
            adj_vals, adj_rows, adj_cols, x, y);
        int n4 = N_NODES * EMBED_DIM / 4;
        acc_add<<<(n4 + 255) / 256, 256, 0, stream>>>(
            acc, y, (l == N_LAYERS - 1) ? 0.25f : 1.0f);
        float* tmp = x; x = y; y = tmp;
    }
}

// Round 2
// 1928.591 us; speedup vs baseline: 5.6791x; 5.6791x over previous
//
#include <hip/hip_runtime.h>

#define N_USERS   100000
#define N_ITEMS   50000
#define N_NODES   150000
#define EMBED_DIM 64
#define COVER_DIM 512
#define N_EDGES   4000000
#define N_LAYERS  3

// ---------------------------------------------------------------------------
// x[0:N_USERS] = user_emb ; acc = x
// ---------------------------------------------------------------------------
__global__ void build_user_x(const float* __restrict__ user_emb,
                             float* __restrict__ x,
                             float* __restrict__ acc) {
    int i = blockIdx.x * blockDim.x + threadIdx.x;  // float4 index
    const int n4 = N_USERS * EMBED_DIM / 4;
    if (i < n4) {
        float4 v = reinterpret_cast<const float4*>(user_emb)[i];
        reinterpret_cast<float4*>(x)[i]   = v;
        reinterpret_cast<float4*>(acc)[i] = v;
    }
}

// ---------------------------------------------------------------------------
// x_items = item_emb + has_cover * (item_cover @ W^T) ; acc_items = x_items
// 16 threads/item, each computing one float4 of the 64-dim output.
// ---------------------------------------------------------------------------
__global__ void build_item_x(const float* __restrict__ item_emb,
                             const float* __restrict__ cover_W,
                             const float* __restrict__ item_cover,
                             const float* __restrict__ has_cover,
                             float* __restrict__ x_items,
                             float* __restrict__ acc_items) {
    int t = blockIdx.x * blockDim.x + threadIdx.x;
    int item = t >> 4;
    int d4   = t & 15;
    if (item >= N_ITEMS) return;

    float hc = has_cover[item];
    const float4* ic = reinterpret_cast<const float4*>(item_cover + (size_t)item * COVER_DIM);
    const float4* w0 = reinterpret_cast<const float4*>(cover_W + (size_t)(d4 * 4 + 0) * COVER_DIM);
    const float4* w1 = reinterpret_cast<const float4*>(cover_W + (size_t)(d4 * 4 + 1) * COVER_DIM);
    const float4* w2 = reinterpret_cast<const float4*>(cover_W + (size_t)(d4 * 4 + 2) * COVER_DIM);
    const float4* w3 = reinterpret_cast<const float4*>(cover_W + (size_t)(d4 * 4 + 3) * COVER_DIM);

    float a0 = 0.f, a1 = 0.f, a2 = 0.f, a3 = 0.f;
#pragma unroll 4
    for (int k = 0; k < COVER_DIM / 4; ++k) {
        float4 c  = ic[k];
        float4 u0 = w0[k], u1 = w1[k], u2 = w2[k], u3 = w3[k];
        a0 += c.x * u0.x + c.y * u0.y + c.z * u0.z + c.w * u0.w;
        a1 += c.x * u1.x + c.y * u1.y + c.z * u1.z + c.w * u1.w;
        a2 += c.x * u2.x + c.y * u2.y + c.z * u2.z + c.w * u2.w;
        a3 += c.x * u3.x + c.y * u3.y + c.z * u3.z + c.w * u3.w;
    }

    float4 e = reinterpret_cast<const float4*>(item_emb)[(size_t)item * 16 + d4];
    float4 r;
    r.x = e.x + hc * a0;
    r.y = e.y + hc * a1;
    r.z = e.z + hc * a2;
    r.w = e.w + hc * a3;
    reinterpret_cast<float4*>(x_items)[(size_t)item * 16 + d4]   = r;
    reinterpret_cast<float4*>(acc_items)[(size_t)item * 16 + d4] = r;
}

// ---------------------------------------------------------------------------
// CSR build: histogram -> single-workgroup scan -> scatter (counting sort).
// ---------------------------------------------------------------------------
__global__ void edge_count(const int* __restrict__ rows, int* __restrict__ cnt) {
    int e = blockIdx.x * blockDim.x + threadIdx.x;
    if (e < N_EDGES) atomicAdd(&cnt[rows[e]], 1);
}

__global__ __launch_bounds__(1024) void scan_rowptr(const int* __restrict__ cnt,
                                                    int* __restrict__ row_ptr,
                                                    int* __restrict__ cursor) {
    __shared__ int sums[1024];
    int tid = threadIdx.x;
    const int CH = (N_NODES + 1023) / 1024;  // 147
    int lo = tid * CH;
    int hi = lo + CH; if (hi > N_NODES) hi = N_NODES;

    int s = 0;
    for (int i = lo; i < hi; ++i) s += cnt[i];
    sums[tid] = s;
    __syncthreads();
    for (int off = 1; off < 1024; off <<= 1) {
        int v = (tid >= off) ? sums[tid - off] : 0;
        __syncthreads();
        sums[tid] += v;
        __syncthreads();
    }
    int base = (tid == 0) ? 0 : sums[tid - 1];
    for (int i = lo; i < hi; ++i) {
        row_ptr[i] = base;
        cursor[i]  = base;
        base += cnt[i];
    }
    if (tid == 0) row_ptr[N_NODES] = sums[1023];
}

// ecv[pos] = (val, col) packed; pos from per-row cursor.
__global__ void edge_scatter(const int* __restrict__ rows,
                             const int* __restrict__ cols,
                             const float* __restrict__ vals,
                             int* __restrict__ cursor,
                             float2* __restrict__ ecv) {
    int e = blockIdx.x * blockDim.x + threadIdx.x;
    if (e >= N_EDGES) return;
    int r = rows[e];
    int pos = atomicAdd(&cursor[r], 1);
    float2 cv;
    cv.x = vals[e];
    cv.y = __int_as_float(cols[e]);
    ecv[pos] = cv;
}

// ---------------------------------------------------------------------------
// CSR SpMM, one wave per row. Quarter-wave (16 lanes) handles one edge at a
// time (4 edges in flight per wave); lane reads a float4 of x[col].
// Fused: y[row] = sum; acc[row] = (acc[row] + sum) * scale.
// ---------------------------------------------------------------------------
__global__ __launch_bounds__(256) void spmm_csr(const int* __restrict__ row_ptr,
                                                const float2* __restrict__ ecv,
                                                const float* __restrict__ x,
                                                float* __restrict__ y,
                                                float* __restrict__ acc,
                                                float scale, int write_y) {
    int wave = (int)((blockIdx.x * blockDim.x + threadIdx.x) >> 6);
    int lane = threadIdx.x & 63;
    if (wave >= N_NODES) return;
    int row  = wave;
    int beg  = row_ptr[row];
    int end  = row_ptr[row + 1];
    int esub = lane >> 4;    // 0..3: which edge of the group of 4
    int p    = lane & 15;    // which float4 of the 64-dim row

    float4 a = make_float4(0.f, 0.f, 0.f, 0.f);
    for (int j = beg + esub; j < end; j += 4) {
        float2 cv = ecv[j];
        int c = __float_as_int(cv.y);
        float4 xv = reinterpret_cast<const float4*>(x)[(size_t)c * 16 + p];
        a.x += cv.x * xv.x;
        a.y += cv.x * xv.y;
        a.z += cv.x * xv.z;
        a.w += cv.x * xv.w;
    }
    // reduce the 4 esub groups (lanes differing in bits 4 and 5)
#pragma unroll
    for (int m = 16; m <= 32; m <<= 1) {
        a.x += __shfl_xor(a.x, m, 64);
        a.y += __shfl_xor(a.y, m, 64);
        a.z += __shfl_xor(a.z, m, 64);
        a.w += __shfl_xor(a.w, m, 64);
    }
    if (esub == 0) {
        size_t idx = (size_t)row * 16 + p;
        if (write_y) reinterpret_cast<float4*>(y)[idx] = a;
        float4 av = reinterpret_cast<float4*>(acc)[idx];
        av.x = (av.x + a.x) * scale;
        av.y = (av.y + a.y) * scale;
        av.z = (av.z + a.z) * scale;
        av.w = (av.w + a.w) * scale;
        reinterpret_cast<float4*>(acc)[idx] = av;
    }
}

// ---------------------------------------------------------------------------
// Fallback path (atomics) if ws_size is too small for CSR buffers.
// ---------------------------------------------------------------------------
__global__ void spmm_atomic(const float* __restrict__ vals,
                            const int* __restrict__ rows,
                            const int* __restrict__ cols,
                            const float* __restrict__ x,
                            float* __restrict__ y) {
    long long t = (long long)blockIdx.x * blockDim.x + threadIdx.x;
    int e    = (int)(t >> 4);
    int part = (int)(t & 15);
    if (e >= N_EDGES) return;
    float v = vals[e];
    int c = cols[e];
    int r = rows[e];
    float4 xa = reinterpret_cast<const float4*>(x)[(size_t)c * 16 + part];
    float* yp = y + (size_t)r * EMBED_DIM + part * 4;
    atomicAdd(yp + 0, v * xa.x);
    atomicAdd(yp + 1, v * xa.y);
    atomicAdd(yp + 2, v * xa.z);
    atomicAdd(yp + 3, v * xa.w);
}

__global__ void acc_add(float* __restrict__ acc,
                        const float* __restrict__ y,
                        float scale) {
    int i = blockIdx.x * blockDim.x + threadIdx.x;
    const int n4 = N_NODES * EMBED_DIM / 4;
    if (i < n4) {
        float4 a = reinterpret_cast<float4*>(acc)[i];
        float4 b = reinterpret_cast<const float4*>(y)[i];
        a.x = (a.x + b.x) * scale;
        a.y = (a.y + b.y) * scale;
        a.z = (a.z + b.z) * scale;
        a.w = (a.w + b.w) * scale;
        reinterpret_cast<float4*>(acc)[i] = a;
    }
}

extern "C" void kernel_launch(void* const* d_in, const int* in_sizes, int n_in,
                              void* d_out, int out_size, void* d_ws, size_t ws_size,
                              hipStream_t stream) {
    const float* user_emb   = (const float*)d_in[0];
    const float* item_emb   = (const float*)d_in[1];
    const float* cover_W    = (const float*)d_in[2];
    const float* item_cover = (const float*)d_in[3];
    const float* has_cover  = (const float*)d_in[4];
    const float* adj_vals   = (const float*)d_in[5];
    const int*   adj_rows   = (const int*)d_in[6];
    const int*   adj_cols   = (const int*)d_in[7];

    float* acc = (float*)d_out;  // [N_NODES][64]

    const size_t feat_elems = (size_t)N_NODES * EMBED_DIM;       // 9.6M floats
    const size_t feat_bytes = feat_elems * sizeof(float);        // 38.4 MB

    // ws layout (256B-aligned chunks):
    //   x (38.4MB) | y (38.4MB) | ecv (32MB) | row_ptr | cnt | cursor
    char* base = (char*)d_ws;
    size_t off = 0;
    auto take = [&](size_t bytes) {
        char* p = base + off;
        off += (bytes + 255) & ~(size_t)255;
        return p;
    };
    float*  x       = (float*)take(feat_bytes);
    float*  y       = (float*)take(feat_bytes);
    float2* ecv     = (float2*)take((size_t)N_EDGES * sizeof(float2));
    int*    row_ptr = (int*)take((size_t)(N_NODES + 1) * sizeof(int));
    int*    cnt     = (int*)take((size_t)N_NODES * sizeof(int));
    int*    cursor  = (int*)take((size_t)N_NODES * sizeof(int));
    bool use_csr = (off <= ws_size);

    // ---- x0 = concat(user_emb, item_emb + cover_proj); acc = x0 ----
    {
        int n4 = N_USERS * EMBED_DIM / 4;
        build_user_x<<<(n4 + 255) / 256, 256, 0, stream>>>(user_emb, x, acc);
    }
    {
        int nt = N_ITEMS * 16;
        build_item_x<<<(nt + 255) / 256, 256, 0, stream>>>(
            item_emb, cover_W, item_cover, has_cover,
            x + (size_t)N_USERS * EMBED_DIM,
            acc + (size_t)N_USERS * EMBED_DIM);
    }

    if (use_csr) {
        // ---- CSR build (once; reused for all 3 layers) ----
        hipMemsetAsync(cnt, 0, (size_t)N_NODES * sizeof(int), stream);
        edge_count<<<(N_EDGES + 255) / 256, 256, 0, stream>>>(adj_rows, cnt);
        scan_rowptr<<<1, 1024, 0, stream>>>(cnt, row_ptr, cursor);
        edge_scatter<<<(N_EDGES + 255) / 256, 256, 0, stream>>>(
            adj_rows, adj_cols, adj_vals, cursor, ecv);

        // ---- 3 propagation layers, acc update fused ----
        for (int l = 0; l < N_LAYERS; ++l) {
            bool last = (l == N_LAYERS - 1);
            int waves_per_block = 256 / 64;
            int grid = (N_NODES + waves_per_block - 1) / waves_per_block;
            spmm_csr<<<grid, 256, 0, stream>>>(
                row_ptr, ecv, x, y, acc,
                last ? 0.25f : 1.0f, last ? 0 : 1);
            float* tmp = x; x = y; y = tmp;
        }
    } else {
        // ---- fallback: fp32-atomic path ----
        for (int l = 0; l < N_LAYERS; ++l) {
            hipMemsetAsync(y, 0, feat_bytes, stream);
            long long nt = (long long)N_EDGES * 16;
            spmm_atomic<<<(int)((nt + 255) / 256), 256, 0, stream>>>(
                adj_vals, adj_rows, adj_cols, x, y);
            int n4 = N_NODES * EMBED_DIM / 4;
            acc_add<<<(n4 + 255) / 256, 256, 0, stream>>>(
                acc, y, (l == N_LAYERS - 1) ? 0.25f : 1.0f);
            float* tmp = x; x = y; y = tmp;
        }
    }
}

// Round 3
// 1370.589 us; speedup vs baseline: 7.9912x; 1.4071x over previous
//
#include <hip/hip_runtime.h>

#define N_USERS   100000
#define N_ITEMS   50000
#define N_NODES   150000
#define EMBED_DIM 64
#define COVER_DIM 512
#define N_EDGES   4000000
#define N_LAYERS  3

// ---------------------------------------------------------------------------
// x[0:N_USERS] = user_emb ; acc = x
// ---------------------------------------------------------------------------
__global__ void build_user_x(const float* __restrict__ user_emb,
                             float* __restrict__ x,
                             float* __restrict__ acc) {
    int i = blockIdx.x * blockDim.x + threadIdx.x;  // float4 index
    const int n4 = N_USERS * EMBED_DIM / 4;
    if (i < n4) {
        float4 v = reinterpret_cast<const float4*>(user_emb)[i];
        reinterpret_cast<float4*>(x)[i]   = v;
        reinterpret_cast<float4*>(acc)[i] = v;
    }
}

// ---------------------------------------------------------------------------
// Tiled fp32 GEMM: proj = item_cover[50000x512] @ W^T[512x64]
// fused epilogue: out = item_emb + has_cover * proj  -> x_items, acc_items
// Block 256 threads, tile M=128 x N=64(full) x K=64.
// LDS: As[128][68] + Bs[64][68] = 51 KB -> 3 blocks/CU.
// Thread (tx,ty): tx=dim-group (4 dims), ty=item sub-row; 8 items x 4 dims.
// ---------------------------------------------------------------------------
#define MT 128
#define KT 64

__global__ __launch_bounds__(256) void build_item_x_tiled(
        const float* __restrict__ item_emb,
        const float* __restrict__ cover_W,
        const float* __restrict__ item_cover,
        const float* __restrict__ has_cover,
        float* __restrict__ x_items,
        float* __restrict__ acc_items) {
    __shared__ float As[MT][KT + 4];           // 128 x 68
    __shared__ float Bs[KT][EMBED_DIM + 4];    // Bs[k][d] = W[d][k0+k]

    const int tid = threadIdx.x;
    const int m0  = blockIdx.x * MT;
    const int tx  = tid & 15;    // d0 = tx*4
    const int ty  = tid >> 4;    // 0..15

    float acc[8][4] = {};

    for (int k0 = 0; k0 < COVER_DIM; k0 += KT) {
        // stage A tile: 128 rows x 64 cols, coalesced float4 (clamped rows)
#pragma unroll
        for (int j = 0; j < 8; ++j) {
            int q  = tid + j * 256;       // 0..2047
            int r  = q >> 4;              // 0..127
            int c4 = q & 15;              // 0..15
            int row = m0 + r;
            if (row >= N_ITEMS) row = N_ITEMS - 1;   // clamp (safe dup read)
            float4 v = *reinterpret_cast<const float4*>(
                item_cover + (size_t)row * COVER_DIM + k0 + c4 * 4);
            *reinterpret_cast<float4*>(&As[r][c4 * 4]) = v;
        }
        // stage B tile transposed: W[d][k0+k] -> Bs[k][d]
#pragma unroll
        for (int j = 0; j < 4; ++j) {
            int q  = tid + j * 256;       // 0..1023
            int d  = q >> 4;              // 0..63
            int c4 = q & 15;
            float4 v = *reinterpret_cast<const float4*>(
                cover_W + (size_t)d * COVER_DIM + k0 + c4 * 4);
            Bs[c4 * 4 + 0][d] = v.x;
            Bs[c4 * 4 + 1][d] = v.y;
            Bs[c4 * 4 + 2][d] = v.z;
            Bs[c4 * 4 + 3][d] = v.w;
        }
        __syncthreads();

        // inner product: k in steps of 4, float4 LDS reads both sides
#pragma unroll
        for (int k = 0; k < KT; k += 4) {
            float4 b0 = *reinterpret_cast<const float4*>(&Bs[k + 0][tx * 4]);
            float4 b1 = *reinterpret_cast<const float4*>(&Bs[k + 1][tx * 4]);
            float4 b2 = *reinterpret_cast<const float4*>(&Bs[k + 2][tx * 4]);
            float4 b3 = *reinterpret_cast<const float4*>(&Bs[k + 3][tx * 4]);
#pragma unroll
            for (int r = 0; r < 8; ++r) {
                float4 a = *reinterpret_cast<const float4*>(&As[ty + r * 16][k]);
                acc[r][0] += a.x * b0.x + a.y * b1.x + a.z * b2.x + a.w * b3.x;
                acc[r][1] += a.x * b0.y + a.y * b1.y + a.z * b2.y + a.w * b3.y;
                acc[r][2] += a.x * b0.z + a.y * b1.z + a.z * b2.z + a.w * b3.z;
                acc[r][3] += a.x * b0.w + a.y * b1.w + a.z * b2.w + a.w * b3.w;
            }
        }
        __syncthreads();
    }

    // epilogue: out = item_emb + has_cover * proj
#pragma unroll
    for (int r = 0; r < 8; ++r) {
        int item = m0 + ty + r * 16;
        if (item < N_ITEMS) {
            float hc = has_cover[item];
            size_t idx = (size_t)item * 16 + tx;   // float4 index
            float4 e = reinterpret_cast<const float4*>(item_emb)[idx];
            float4 o;
            o.x = e.x + hc * acc[r][0];
            o.y = e.y + hc * acc[r][1];
            o.z = e.z + hc * acc[r][2];
            o.w = e.w + hc * acc[r][3];
            reinterpret_cast<float4*>(x_items)[idx]   = o;
            reinterpret_cast<float4*>(acc_items)[idx] = o;
        }
    }
}

// ---------------------------------------------------------------------------
// CSR build: histogram -> single-workgroup scan -> scatter (counting sort).
// ---------------------------------------------------------------------------
__global__ void edge_count(const int* __restrict__ rows, int* __restrict__ cnt) {
    int e = blockIdx.x * blockDim.x + threadIdx.x;
    if (e < N_EDGES) atomicAdd(&cnt[rows[e]], 1);
}

__global__ __launch_bounds__(1024) void scan_rowptr(const int* __restrict__ cnt,
                                                    int* __restrict__ row_ptr,
                                                    int* __restrict__ cursor) {
    __shared__ int sums[1024];
    int tid = threadIdx.x;
    const int CH = (N_NODES + 1023) / 1024;  // 147
    int lo = tid * CH;
    int hi = lo + CH; if (hi > N_NODES) hi = N_NODES;

    int s = 0;
    for (int i = lo; i < hi; ++i) s += cnt[i];
    sums[tid] = s;
    __syncthreads();
    for (int off = 1; off < 1024; off <<= 1) {
        int v = (tid >= off) ? sums[tid - off] : 0;
        __syncthreads();
        sums[tid] += v;
        __syncthreads();
    }
    int base = (tid == 0) ? 0 : sums[tid - 1];
    for (int i = lo; i < hi; ++i) {
        row_ptr[i] = base;
        cursor[i]  = base;
        base += cnt[i];
    }
    if (tid == 0) row_ptr[N_NODES] = sums[1023];
}

// ecv[pos] = (val, col) packed; pos from per-row cursor.
__global__ void edge_scatter(const int* __restrict__ rows,
                             const int* __restrict__ cols,
                             const float* __restrict__ vals,
                             int* __restrict__ cursor,
                             float2* __restrict__ ecv) {
    int e = blockIdx.x * blockDim.x + threadIdx.x;
    if (e >= N_EDGES) return;
    int r = rows[e];
    int pos = atomicAdd(&cursor[r], 1);
    float2 cv;
    cv.x = vals[e];
    cv.y = __int_as_float(cols[e]);
    ecv[pos] = cv;
}

// ---------------------------------------------------------------------------
// CSR SpMM, one wave per row. Quarter-wave (16 lanes) handles one edge at a
// time (4 edges in flight per wave); lane reads a float4 of x[col].
// Fused: y[row] = sum; acc[row] = (acc[row] + sum) * scale.
// ---------------------------------------------------------------------------
__global__ __launch_bounds__(256) void spmm_csr(const int* __restrict__ row_ptr,
                                                const float2* __restrict__ ecv,
                                                const float* __restrict__ x,
                                                float* __restrict__ y,
                                                float* __restrict__ acc,
                                                float scale, int write_y) {
    int wave = (int)((blockIdx.x * blockDim.x + threadIdx.x) >> 6);
    int lane = threadIdx.x & 63;
    if (wave >= N_NODES) return;
    int row  = wave;
    int beg  = row_ptr[row];
    int end  = row_ptr[row + 1];
    int esub = lane >> 4;    // 0..3: which edge of the group of 4
    int p    = lane & 15;    // which float4 of the 64-dim row

    float4 a = make_float4(0.f, 0.f, 0.f, 0.f);
    for (int j = beg + esub; j < end; j += 4) {
        float2 cv = ecv[j];
        int c = __float_as_int(cv.y);
        float4 xv = reinterpret_cast<const float4*>(x)[(size_t)c * 16 + p];
        a.x += cv.x * xv.x;
        a.y += cv.x * xv.y;
        a.z += cv.x * xv.z;
        a.w += cv.x * xv.w;
    }
    // reduce the 4 esub groups (lanes differing in bits 4 and 5)
#pragma unroll
    for (int m = 16; m <= 32; m <<= 1) {
        a.x += __shfl_xor(a.x, m, 64);
        a.y += __shfl_xor(a.y, m, 64);
        a.z += __shfl_xor(a.z, m, 64);
        a.w += __shfl_xor(a.w, m, 64);
    }
    if (esub == 0) {
        size_t idx = (size_t)row * 16 + p;
        if (write_y) reinterpret_cast<float4*>(y)[idx] = a;
        float4 av = reinterpret_cast<float4*>(acc)[idx];
        av.x = (av.x + a.x) * scale;
        av.y = (av.y + a.y) * scale;
        av.z = (av.z + a.z) * scale;
        av.w = (av.w + a.w) * scale;
        reinterpret_cast<float4*>(acc)[idx] = av;
    }
}

// ---------------------------------------------------------------------------
// Fallback path (atomics) if ws_size is too small for CSR buffers.
// ---------------------------------------------------------------------------
__global__ void spmm_atomic(const float* __restrict__ vals,
                            const int* __restrict__ rows,
                            const int* __restrict__ cols,
                            const float* __restrict__ x,
                            float* __restrict__ y) {
    long long t = (long long)blockIdx.x * blockDim.x + threadIdx.x;
    int e    = (int)(t >> 4);
    int part = (int)(t & 15);
    if (e >= N_EDGES) return;
    float v = vals[e];
    int c = cols[e];
    int r = rows[e];
    float4 xa = reinterpret_cast<const float4*>(x)[(size_t)c * 16 + part];
    float* yp = y + (size_t)r * EMBED_DIM + part * 4;
    atomicAdd(yp + 0, v * xa.x);
    atomicAdd(yp + 1, v * xa.y);
    atomicAdd(yp + 2, v * xa.z);
    atomicAdd(yp + 3, v * xa.w);
}

__global__ void acc_add(float* __restrict__ acc,
                        const float* __restrict__ y,
                        float scale) {
    int i = blockIdx.x * blockDim.x + threadIdx.x;
    const int n4 = N_NODES * EMBED_DIM / 4;
    if (i < n4) {
        float4 a = reinterpret_cast<float4*>(acc)[i];
        float4 b = reinterpret_cast<const float4*>(y)[i];
        a.x = (a.x + b.x) * scale;
        a.y = (a.y + b.y) * scale;
        a.z = (a.z + b.z) * scale;
        a.w = (a.w + b.w) * scale;
        reinterpret_cast<float4*>(acc)[i] = a;
    }
}

extern "C" void kernel_launch(void* const* d_in, const int* in_sizes, int n_in,
                              void* d_out, int out_size, void* d_ws, size_t ws_size,
                              hipStream_t stream) {
    const float* user_emb   = (const float*)d_in[0];
    const float* item_emb   = (const float*)d_in[1];
    const float* cover_W    = (const float*)d_in[2];
    const float* item_cover = (const float*)d_in[3];
    const float* has_cover  = (const float*)d_in[4];
    const float* adj_vals   = (const float*)d_in[5];
    const int*   adj_rows   = (const int*)d_in[6];
    const int*   adj_cols   = (const int*)d_in[7];

    float* acc = (float*)d_out;  // [N_NODES][64]

    const size_t feat_elems = (size_t)N_NODES * EMBED_DIM;       // 9.6M floats
    const size_t feat_bytes = feat_elems * sizeof(float);        // 38.4 MB

    char* base = (char*)d_ws;
    size_t off = 0;
    auto take = [&](size_t bytes) {
        char* p = base + off;
        off += (bytes + 255) & ~(size_t)255;
        return p;
    };
    float*  x       = (float*)take(feat_bytes);
    float*  y       = (float*)take(feat_bytes);
    float2* ecv     = (float2*)take((size_t)N_EDGES * sizeof(float2));
    int*    row_ptr = (int*)take((size_t)(N_NODES + 1) * sizeof(int));
    int*    cnt     = (int*)take((size_t)N_NODES * sizeof(int));
    int*    cursor  = (int*)take((size_t)N_NODES * sizeof(int));
    bool use_csr = (off <= ws_size);

    // ---- x0 = concat(user_emb, item_emb + cover_proj); acc = x0 ----
    {
        int n4 = N_USERS * EMBED_DIM / 4;
        build_user_x<<<(n4 + 255) / 256, 256, 0, stream>>>(user_emb, x, acc);
    }
    {
        int grid = (N_ITEMS + MT - 1) / MT;   // 391
        build_item_x_tiled<<<grid, 256, 0, stream>>>(
            item_emb, cover_W, item_cover, has_cover,
            x + (size_t)N_USERS * EMBED_DIM,
            acc + (size_t)N_USERS * EMBED_DIM);
    }

    if (use_csr) {
        // ---- CSR build (once; reused for all 3 layers) ----
        hipMemsetAsync(cnt, 0, (size_t)N_NODES * sizeof(int), stream);
        edge_count<<<(N_EDGES + 255) / 256, 256, 0, stream>>>(adj_rows, cnt);
        scan_rowptr<<<1, 1024, 0, stream>>>(cnt, row_ptr, cursor);
        edge_scatter<<<(N_EDGES + 255) / 256, 256, 0, stream>>>(
            adj_rows, adj_cols, adj_vals, cursor, ecv);

        // ---- 3 propagation layers, acc update fused ----
        for (int l = 0; l < N_LAYERS; ++l) {
            bool last = (l == N_LAYERS - 1);
            int waves_per_block = 256 / 64;
            int grid = (N_NODES + waves_per_block - 1) / waves_per_block;
            spmm_csr<<<grid, 256, 0, stream>>>(
                row_ptr, ecv, x, y, acc,
                last ? 0.25f : 1.0f, last ? 0 : 1);
            float* tmp = x; x = y; y = tmp;
        }
    } else {
        // ---- fallback: fp32-atomic path ----
        for (int l = 0; l < N_LAYERS; ++l) {
            hipMemsetAsync(y, 0, feat_bytes, stream);
            long long nt = (long long)N_EDGES * 16;
            spmm_atomic<<<(int)((nt + 255) / 256), 256, 0, stream>>>(
                adj_vals, adj_rows, adj_cols, x, y);
            int n4 = N_NODES * EMBED_DIM / 4;
            acc_add<<<(n4 + 255) / 256, 256, 0, stream>>>(
                acc, y, (l == N_LAYERS - 1) ? 0.25f : 1.0f);
            float* tmp = x; x = y; y = tmp;
        }
    }
}

// Round 4
// 1075.103 us; speedup vs baseline: 10.1875x; 1.2748x over previous
//
#include <hip/hip_runtime.h>

#define N_USERS   100000
#define N_ITEMS   50000
#define N_NODES   150000
#define EMBED_DIM 64
#define COVER_DIM 512
#define N_EDGES   4000000
#define N_LAYERS  3

// ---------------------------------------------------------------------------
// x[0:N_USERS] = user_emb ; acc = x
// ---------------------------------------------------------------------------
__global__ void build_user_x(const float* __restrict__ user_emb,
                             float* __restrict__ x,
                             float* __restrict__ acc) {
    int i = blockIdx.x * blockDim.x + threadIdx.x;  // float4 index
    const int n4 = N_USERS * EMBED_DIM / 4;
    if (i < n4) {
        float4 v = reinterpret_cast<const float4*>(user_emb)[i];
        reinterpret_cast<float4*>(x)[i]   = v;
        reinterpret_cast<float4*>(acc)[i] = v;
    }
}

// ---------------------------------------------------------------------------
// Tiled fp32 GEMM: proj = item_cover[50000x512] @ W^T[512x64]
// fused epilogue: out = item_emb + has_cover * proj  -> x_items, acc_items
// ---------------------------------------------------------------------------
#define MT 128
#define KT 64

__global__ __launch_bounds__(256) void build_item_x_tiled(
        const float* __restrict__ item_emb,
        const float* __restrict__ cover_W,
        const float* __restrict__ item_cover,
        const float* __restrict__ has_cover,
        float* __restrict__ x_items,
        float* __restrict__ acc_items) {
    __shared__ float As[MT][KT + 4];           // 128 x 68
    __shared__ float Bs[KT][EMBED_DIM + 4];    // Bs[k][d] = W[d][k0+k]

    const int tid = threadIdx.x;
    const int m0  = blockIdx.x * MT;
    const int tx  = tid & 15;    // d0 = tx*4
    const int ty  = tid >> 4;    // 0..15

    float acc[8][4] = {};

    for (int k0 = 0; k0 < COVER_DIM; k0 += KT) {
#pragma unroll
        for (int j = 0; j < 8; ++j) {
            int q  = tid + j * 256;       // 0..2047
            int r  = q >> 4;              // 0..127
            int c4 = q & 15;              // 0..15
            int row = m0 + r;
            if (row >= N_ITEMS) row = N_ITEMS - 1;
            float4 v = *reinterpret_cast<const float4*>(
                item_cover + (size_t)row * COVER_DIM + k0 + c4 * 4);
            *reinterpret_cast<float4*>(&As[r][c4 * 4]) = v;
        }
#pragma unroll
        for (int j = 0; j < 4; ++j) {
            int q  = tid + j * 256;       // 0..1023
            int d  = q >> 4;              // 0..63
            int c4 = q & 15;
            float4 v = *reinterpret_cast<const float4*>(
                cover_W + (size_t)d * COVER_DIM + k0 + c4 * 4);
            Bs[c4 * 4 + 0][d] = v.x;
            Bs[c4 * 4 + 1][d] = v.y;
            Bs[c4 * 4 + 2][d] = v.z;
            Bs[c4 * 4 + 3][d] = v.w;
        }
        __syncthreads();

#pragma unroll
        for (int k = 0; k < KT; k += 4) {
            float4 b0 = *reinterpret_cast<const float4*>(&Bs[k + 0][tx * 4]);
            float4 b1 = *reinterpret_cast<const float4*>(&Bs[k + 1][tx * 4]);
            float4 b2 = *reinterpret_cast<const float4*>(&Bs[k + 2][tx * 4]);
            float4 b3 = *reinterpret_cast<const float4*>(&Bs[k + 3][tx * 4]);
#pragma unroll
            for (int r = 0; r < 8; ++r) {
                float4 a = *reinterpret_cast<const float4*>(&As[ty + r * 16][k]);
                acc[r][0] += a.x * b0.x + a.y * b1.x + a.z * b2.x + a.w * b3.x;
                acc[r][1] += a.x * b0.y + a.y * b1.y + a.z * b2.y + a.w * b3.y;
                acc[r][2] += a.x * b0.z + a.y * b1.z + a.z * b2.z + a.w * b3.z;
                acc[r][3] += a.x * b0.w + a.y * b1.w + a.z * b2.w + a.w * b3.w;
            }
        }
        __syncthreads();
    }

#pragma unroll
    for (int r = 0; r < 8; ++r) {
        int item = m0 + ty + r * 16;
        if (item < N_ITEMS) {
            float hc = has_cover[item];
            size_t idx = (size_t)item * 16 + tx;   // float4 index
            float4 e = reinterpret_cast<const float4*>(item_emb)[idx];
            float4 o;
            o.x = e.x + hc * acc[r][0];
            o.y = e.y + hc * acc[r][1];
            o.z = e.z + hc * acc[r][2];
            o.w = e.w + hc * acc[r][3];
            reinterpret_cast<float4*>(x_items)[idx]   = o;
            reinterpret_cast<float4*>(acc_items)[idx] = o;
        }
    }
}

// ---------------------------------------------------------------------------
// CSR build: histogram -> hierarchical scan (3 small kernels) -> scatter.
// ---------------------------------------------------------------------------
__global__ void edge_count(const int* __restrict__ rows, int* __restrict__ cnt) {
    int e = blockIdx.x * blockDim.x + threadIdx.x;
    if (e < N_EDGES) atomicAdd(&cnt[rows[e]], 1);
}

#define SCAN_CHUNK 1024
#define SCAN_NBLK  ((N_NODES + SCAN_CHUNK - 1) / SCAN_CHUNK)   // 147

// A: per-block local exclusive scan of a 1024-elem chunk of cnt -> row_ptr,
//    block total -> bsum[b]. 256 threads, 4 elems/thread, int4.
__global__ __launch_bounds__(256) void scan_local(const int* __restrict__ cnt,
                                                  int* __restrict__ row_ptr,
                                                  int* __restrict__ bsum) {
    __shared__ int tsum[256];
    const int b   = blockIdx.x;
    const int tid = threadIdx.x;
    const int i0  = b * SCAN_CHUNK + tid * 4;

    int v0 = 0, v1 = 0, v2 = 0, v3 = 0;
    if (i0 + 3 < N_NODES) {
        int4 v = *reinterpret_cast<const int4*>(cnt + i0);
        v0 = v.x; v1 = v.y; v2 = v.z; v3 = v.w;
    } else {
        if (i0 + 0 < N_NODES) v0 = cnt[i0 + 0];
        if (i0 + 1 < N_NODES) v1 = cnt[i0 + 1];
        if (i0 + 2 < N_NODES) v2 = cnt[i0 + 2];
        if (i0 + 3 < N_NODES) v3 = cnt[i0 + 3];
    }
    tsum[tid] = v0 + v1 + v2 + v3;
    __syncthreads();
    for (int off = 1; off < 256; off <<= 1) {
        int t = (tid >= off) ? tsum[tid - off] : 0;
        __syncthreads();
        tsum[tid] += t;
        __syncthreads();
    }
    int e0 = (tid == 0) ? 0 : tsum[tid - 1];
    int e1 = e0 + v0;
    int e2 = e1 + v1;
    int e3 = e2 + v2;
    if (i0 + 3 < N_NODES) {
        *reinterpret_cast<int4*>(row_ptr + i0) = make_int4(e0, e1, e2, e3);
    } else {
        if (i0 + 0 < N_NODES) row_ptr[i0 + 0] = e0;
        if (i0 + 1 < N_NODES) row_ptr[i0 + 1] = e1;
        if (i0 + 2 < N_NODES) row_ptr[i0 + 2] = e2;
        if (i0 + 3 < N_NODES) row_ptr[i0 + 3] = e3;
    }
    if (tid == 255) bsum[b] = tsum[255];
}

// B: single block scans the SCAN_NBLK block totals -> exclusive offsets in
//    place; writes grand total to row_ptr[N_NODES].
__global__ __launch_bounds__(256) void scan_bsums(int* __restrict__ bsum,
                                                  int* __restrict__ row_ptr) {
    __shared__ int s[256];
    int tid = threadIdx.x;
    int v = (tid < SCAN_NBLK) ? bsum[tid] : 0;
    s[tid] = v;
    __syncthreads();
    for (int off = 1; off < 256; off <<= 1) {
        int t = (tid >= off) ? s[tid - off] : 0;
        __syncthreads();
        s[tid] += t;
        __syncthreads();
    }
    if (tid < SCAN_NBLK) bsum[tid] = (tid == 0) ? 0 : s[tid - 1];
    if (tid == 255) row_ptr[N_NODES] = s[255];
}

// C: add block offsets in place; mirror into cursor.
__global__ __launch_bounds__(256) void scan_apply(int* __restrict__ row_ptr,
                                                  const int* __restrict__ bsum,
                                                  int* __restrict__ cursor) {
    const int b   = blockIdx.x;
    const int off = bsum[b];
    const int i0  = b * SCAN_CHUNK + threadIdx.x * 4;
    if (i0 + 3 < N_NODES) {
        int4 v = *reinterpret_cast<int4*>(row_ptr + i0);
        v.x += off; v.y += off; v.z += off; v.w += off;
        *reinterpret_cast<int4*>(row_ptr + i0) = v;
        *reinterpret_cast<int4*>(cursor + i0)  = v;
    } else {
#pragma unroll
        for (int j = 0; j < 4; ++j) {
            if (i0 + j < N_NODES) {
                int t = row_ptr[i0 + j] + off;
                row_ptr[i0 + j] = t;
                cursor[i0 + j]  = t;
            }
        }
    }
}

// ecv[pos] = (val, col) packed; pos from per-row cursor.
__global__ void edge_scatter(const int* __restrict__ rows,
                             const int* __restrict__ cols,
                             const float* __restrict__ vals,
                             int* __restrict__ cursor,
                             float2* __restrict__ ecv) {
    int e = blockIdx.x * blockDim.x + threadIdx.x;
    if (e >= N_EDGES) return;
    int r = rows[e];
    int pos = atomicAdd(&cursor[r], 1);
    float2 cv;
    cv.x = vals[e];
    cv.y = __int_as_float(cols[e]);
    ecv[pos] = cv;
}

// ---------------------------------------------------------------------------
// CSR SpMM, one wave per row; quarter-wave per edge; float4 gathers.
// Fused: y[row] = sum; acc[row] = (acc[row] + sum) * scale.
// ---------------------------------------------------------------------------
__global__ __launch_bounds__(256) void spmm_csr(const int* __restrict__ row_ptr,
                                                const float2* __restrict__ ecv,
                                                const float* __restrict__ x,
                                                float* __restrict__ y,
                                                float* __restrict__ acc,
                                                float scale, int write_y) {
    int wave = (int)((blockIdx.x * blockDim.x + threadIdx.x) >> 6);
    int lane = threadIdx.x & 63;
    if (wave >= N_NODES) return;
    int row  = wave;
    int beg  = row_ptr[row];
    int end  = row_ptr[row + 1];
    int esub = lane >> 4;
    int p    = lane & 15;

    float4 a = make_float4(0.f, 0.f, 0.f, 0.f);
    for (int j = beg + esub; j < end; j += 4) {
        float2 cv = ecv[j];
        int c = __float_as_int(cv.y);
        float4 xv = reinterpret_cast<const float4*>(x)[(size_t)c * 16 + p];
        a.x += cv.x * xv.x;
        a.y += cv.x * xv.y;
        a.z += cv.x * xv.z;
        a.w += cv.x * xv.w;
    }
#pragma unroll
    for (int m = 16; m <= 32; m <<= 1) {
        a.x += __shfl_xor(a.x, m, 64);
        a.y += __shfl_xor(a.y, m, 64);
        a.z += __shfl_xor(a.z, m, 64);
        a.w += __shfl_xor(a.w, m, 64);
    }
    if (esub == 0) {
        size_t idx = (size_t)row * 16 + p;
        if (write_y) reinterpret_cast<float4*>(y)[idx] = a;
        float4 av = reinterpret_cast<float4*>(acc)[idx];
        av.x = (av.x + a.x) * scale;
        av.y = (av.y + a.y) * scale;
        av.z = (av.z + a.z) * scale;
        av.w = (av.w + a.w) * scale;
        reinterpret_cast<float4*>(acc)[idx] = av;
    }
}

// ---------------------------------------------------------------------------
// Fallback path (atomics) if ws_size is too small for CSR buffers.
// ---------------------------------------------------------------------------
__global__ void spmm_atomic(const float* __restrict__ vals,
                            const int* __restrict__ rows,
                            const int* __restrict__ cols,
                            const float* __restrict__ x,
                            float* __restrict__ y) {
    long long t = (long long)blockIdx.x * blockDim.x + threadIdx.x;
    int e    = (int)(t >> 4);
    int part = (int)(t & 15);
    if (e >= N_EDGES) return;
    float v = vals[e];
    int c = cols[e];
    int r = rows[e];
    float4 xa = reinterpret_cast<const float4*>(x)[(size_t)c * 16 + part];
    float* yp = y + (size_t)r * EMBED_DIM + part * 4;
    atomicAdd(yp + 0, v * xa.x);
    atomicAdd(yp + 1, v * xa.y);
    atomicAdd(yp + 2, v * xa.z);
    atomicAdd(yp + 3, v * xa.w);
}

__global__ void acc_add(float* __restrict__ acc,
                        const float* __restrict__ y,
                        float scale) {
    int i = blockIdx.x * blockDim.x + threadIdx.x;
    const int n4 = N_NODES * EMBED_DIM / 4;
    if (i < n4) {
        float4 a = reinterpret_cast<float4*>(acc)[i];
        float4 b = reinterpret_cast<const float4*>(y)[i];
        a.x = (a.x + b.x) * scale;
        a.y = (a.y + b.y) * scale;
        a.z = (a.z + b.z) * scale;
        a.w = (a.w + b.w) * scale;
        reinterpret_cast<float4*>(acc)[i] = a;
    }
}

extern "C" void kernel_launch(void* const* d_in, const int* in_sizes, int n_in,
                              void* d_out, int out_size, void* d_ws, size_t ws_size,
                              hipStream_t stream) {
    const float* user_emb   = (const float*)d_in[0];
    const float* item_emb   = (const float*)d_in[1];
    const float* cover_W    = (const float*)d_in[2];
    const float* item_cover = (const float*)d_in[3];
    const float* has_cover  = (const float*)d_in[4];
    const float* adj_vals   = (const float*)d_in[5];
    const int*   adj_rows   = (const int*)d_in[6];
    const int*   adj_cols   = (const int*)d_in[7];

    float* acc = (float*)d_out;  // [N_NODES][64]

    const size_t feat_elems = (size_t)N_NODES * EMBED_DIM;       // 9.6M floats
    const size_t feat_bytes = feat_elems * sizeof(float);        // 38.4 MB

    char* base = (char*)d_ws;
    size_t off = 0;
    auto take = [&](size_t bytes) {
        char* p = base + off;
        off += (bytes + 255) & ~(size_t)255;
        return p;
    };
    float*  x       = (float*)take(feat_bytes);
    float*  y       = (float*)take(feat_bytes);
    float2* ecv     = (float2*)take((size_t)N_EDGES * sizeof(float2));
    int*    row_ptr = (int*)take((size_t)(N_NODES + 1) * sizeof(int));
    int*    cnt     = (int*)take((size_t)N_NODES * sizeof(int));
    int*    cursor  = (int*)take((size_t)N_NODES * sizeof(int));
    int*    bsum    = (int*)take((size_t)SCAN_NBLK * sizeof(int));
    bool use_csr = (off <= ws_size);

    // ---- x0 = concat(user_emb, item_emb + cover_proj); acc = x0 ----
    {
        int n4 = N_USERS * EMBED_DIM / 4;
        build_user_x<<<(n4 + 255) / 256, 256, 0, stream>>>(user_emb, x, acc);
    }
    {
        int grid = (N_ITEMS + MT - 1) / MT;   // 391
        build_item_x_tiled<<<grid, 256, 0, stream>>>(
            item_emb, cover_W, item_cover, has_cover,
            x + (size_t)N_USERS * EMBED_DIM,
            acc + (size_t)N_USERS * EMBED_DIM);
    }

    if (use_csr) {
        // ---- CSR build (once; reused for all 3 layers) ----
        hipMemsetAsync(cnt, 0, (size_t)N_NODES * sizeof(int), stream);
        edge_count<<<(N_EDGES + 255) / 256, 256, 0, stream>>>(adj_rows, cnt);
        scan_local<<<SCAN_NBLK, 256, 0, stream>>>(cnt, row_ptr, bsum);
        scan_bsums<<<1, 256, 0, stream>>>(bsum, row_ptr);
        scan_apply<<<SCAN_NBLK, 256, 0, stream>>>(row_ptr, bsum, cursor);
        edge_scatter<<<(N_EDGES + 255) / 256, 256, 0, stream>>>(
            adj_rows, adj_cols, adj_vals, cursor, ecv);

        // ---- 3 propagation layers, acc update fused ----
        for (int l = 0; l < N_LAYERS; ++l) {
            bool last = (l == N_LAYERS - 1);
            int waves_per_block = 256 / 64;
            int grid = (N_NODES + waves_per_block - 1) / waves_per_block;
            spmm_csr<<<grid, 256, 0, stream>>>(
                row_ptr, ecv, x, y, acc,
                last ? 0.25f : 1.0f, last ? 0 : 1);
            float* tmp = x; x = y; y = tmp;
        }
    } else {
        // ---- fallback: fp32-atomic path ----
        for (int l = 0; l < N_LAYERS; ++l) {
            hipMemsetAsync(y, 0, feat_bytes, stream);
            long long nt = (long long)N_EDGES * 16;
            spmm_atomic<<<(int)((nt + 255) / 256), 256, 0, stream>>>(
                adj_vals, adj_rows, adj_cols, x, y);
            int n4 = N_NODES * EMBED_DIM / 4;
            acc_add<<<(n4 + 255) / 256, 256, 0, stream>>>(
                acc, y, (l == N_LAYERS - 1) ? 0.25f : 1.0f);
            float* tmp = x; x = y; y = tmp;
        }
    }
}

// Round 5
// 1049.456 us; speedup vs baseline: 10.4365x; 1.0244x over previous
//
#include <hip/hip_runtime.h>

#define N_USERS   100000
#define N_ITEMS   50000
#define N_NODES   150000
#define EMBED_DIM 64
#define COVER_DIM 512
#define N_EDGES   4000000
#define N_LAYERS  3

typedef __attribute__((ext_vector_type(4))) _Float16 half4;

// ---------------------------------------------------------------------------
// x16[0:N_USERS] = fp16(user_emb) ; acc = user_emb (fp32)
// ---------------------------------------------------------------------------
__global__ void build_user_x(const float* __restrict__ user_emb,
                             half4* __restrict__ x16,
                             float* __restrict__ acc) {
    int i = blockIdx.x * blockDim.x + threadIdx.x;  // float4 / half4 index
    const int n4 = N_USERS * EMBED_DIM / 4;
    if (i < n4) {
        float4 v = reinterpret_cast<const float4*>(user_emb)[i];
        half4 h;
        h.x = (_Float16)v.x; h.y = (_Float16)v.y;
        h.z = (_Float16)v.z; h.w = (_Float16)v.w;
        x16[i] = h;
        reinterpret_cast<float4*>(acc)[i] = v;
    }
}

// ---------------------------------------------------------------------------
// Tiled fp32 GEMM: proj = item_cover[50000x512] @ W^T[512x64]
// epilogue: o = item_emb + has_cover*proj -> x16 (fp16), acc (fp32)
// ---------------------------------------------------------------------------
#define MT 128
#define KT 64

__global__ __launch_bounds__(256) void build_item_x_tiled(
        const float* __restrict__ item_emb,
        const float* __restrict__ cover_W,
        const float* __restrict__ item_cover,
        const float* __restrict__ has_cover,
        half4* __restrict__ x16_items,
        float* __restrict__ acc_items) {
    __shared__ float As[MT][KT + 4];           // 128 x 68
    __shared__ float Bs[KT][EMBED_DIM + 4];    // Bs[k][d] = W[d][k0+k]

    const int tid = threadIdx.x;
    const int m0  = blockIdx.x * MT;
    const int tx  = tid & 15;    // d0 = tx*4
    const int ty  = tid >> 4;    // 0..15

    float acc[8][4] = {};

    for (int k0 = 0; k0 < COVER_DIM; k0 += KT) {
#pragma unroll
        for (int j = 0; j < 8; ++j) {
            int q  = tid + j * 256;       // 0..2047
            int r  = q >> 4;              // 0..127
            int c4 = q & 15;              // 0..15
            int row = m0 + r;
            if (row >= N_ITEMS) row = N_ITEMS - 1;
            float4 v = *reinterpret_cast<const float4*>(
                item_cover + (size_t)row * COVER_DIM + k0 + c4 * 4);
            *reinterpret_cast<float4*>(&As[r][c4 * 4]) = v;
        }
#pragma unroll
        for (int j = 0; j < 4; ++j) {
            int q  = tid + j * 256;       // 0..1023
            int d  = q >> 4;              // 0..63
            int c4 = q & 15;
            float4 v = *reinterpret_cast<const float4*>(
                cover_W + (size_t)d * COVER_DIM + k0 + c4 * 4);
            Bs[c4 * 4 + 0][d] = v.x;
            Bs[c4 * 4 + 1][d] = v.y;
            Bs[c4 * 4 + 2][d] = v.z;
            Bs[c4 * 4 + 3][d] = v.w;
        }
        __syncthreads();

#pragma unroll
        for (int k = 0; k < KT; k += 4) {
            float4 b0 = *reinterpret_cast<const float4*>(&Bs[k + 0][tx * 4]);
            float4 b1 = *reinterpret_cast<const float4*>(&Bs[k + 1][tx * 4]);
            float4 b2 = *reinterpret_cast<const float4*>(&Bs[k + 2][tx * 4]);
            float4 b3 = *reinterpret_cast<const float4*>(&Bs[k + 3][tx * 4]);
#pragma unroll
            for (int r = 0; r < 8; ++r) {
                float4 a = *reinterpret_cast<const float4*>(&As[ty + r * 16][k]);
                acc[r][0] += a.x * b0.x + a.y * b1.x + a.z * b2.x + a.w * b3.x;
                acc[r][1] += a.x * b0.y + a.y * b1.y + a.z * b2.y + a.w * b3.y;
                acc[r][2] += a.x * b0.z + a.y * b1.z + a.z * b2.z + a.w * b3.z;
                acc[r][3] += a.x * b0.w + a.y * b1.w + a.z * b2.w + a.w * b3.w;
            }
        }
        __syncthreads();
    }

#pragma unroll
    for (int r = 0; r < 8; ++r) {
        int item = m0 + ty + r * 16;
        if (item < N_ITEMS) {
            float hc = has_cover[item];
            size_t idx = (size_t)item * 16 + tx;   // float4/half4 index
            float4 e = reinterpret_cast<const float4*>(item_emb)[idx];
            float4 o;
            o.x = e.x + hc * acc[r][0];
            o.y = e.y + hc * acc[r][1];
            o.z = e.z + hc * acc[r][2];
            o.w = e.w + hc * acc[r][3];
            half4 h;
            h.x = (_Float16)o.x; h.y = (_Float16)o.y;
            h.z = (_Float16)o.z; h.w = (_Float16)o.w;
            x16_items[idx] = h;
            reinterpret_cast<float4*>(acc_items)[idx] = o;
        }
    }
}

// ---------------------------------------------------------------------------
// CSR build: histogram -> hierarchical scan -> scatter.
// ---------------------------------------------------------------------------
__global__ void edge_count(const int* __restrict__ rows, int* __restrict__ cnt) {
    int e = blockIdx.x * blockDim.x + threadIdx.x;
    if (e < N_EDGES) atomicAdd(&cnt[rows[e]], 1);
}

#define SCAN_CHUNK 1024
#define SCAN_NBLK  ((N_NODES + SCAN_CHUNK - 1) / SCAN_CHUNK)   // 147

__global__ __launch_bounds__(256) void scan_local(const int* __restrict__ cnt,
                                                  int* __restrict__ row_ptr,
                                                  int* __restrict__ bsum) {
    __shared__ int tsum[256];
    const int b   = blockIdx.x;
    const int tid = threadIdx.x;
    const int i0  = b * SCAN_CHUNK + tid * 4;

    int v0 = 0, v1 = 0, v2 = 0, v3 = 0;
    if (i0 + 3 < N_NODES) {
        int4 v = *reinterpret_cast<const int4*>(cnt + i0);
        v0 = v.x; v1 = v.y; v2 = v.z; v3 = v.w;
    } else {
        if (i0 + 0 < N_NODES) v0 = cnt[i0 + 0];
        if (i0 + 1 < N_NODES) v1 = cnt[i0 + 1];
        if (i0 + 2 < N_NODES) v2 = cnt[i0 + 2];
        if (i0 + 3 < N_NODES) v3 = cnt[i0 + 3];
    }
    tsum[tid] = v0 + v1 + v2 + v3;
    __syncthreads();
    for (int off = 1; off < 256; off <<= 1) {
        int t = (tid >= off) ? tsum[tid - off] : 0;
        __syncthreads();
        tsum[tid] += t;
        __syncthreads();
    }
    int e0 = (tid == 0) ? 0 : tsum[tid - 1];
    int e1 = e0 + v0;
    int e2 = e1 + v1;
    int e3 = e2 + v2;
    if (i0 + 3 < N_NODES) {
        *reinterpret_cast<int4*>(row_ptr + i0) = make_int4(e0, e1, e2, e3);
    } else {
        if (i0 + 0 < N_NODES) row_ptr[i0 + 0] = e0;
        if (i0 + 1 < N_NODES) row_ptr[i0 + 1] = e1;
        if (i0 + 2 < N_NODES) row_ptr[i0 + 2] = e2;
        if (i0 + 3 < N_NODES) row_ptr[i0 + 3] = e3;
    }
    if (tid == 255) bsum[b] = tsum[255];
}

__global__ __launch_bounds__(256) void scan_bsums(int* __restrict__ bsum,
                                                  int* __restrict__ row_ptr) {
    __shared__ int s[256];
    int tid = threadIdx.x;
    int v = (tid < SCAN_NBLK) ? bsum[tid] : 0;
    s[tid] = v;
    __syncthreads();
    for (int off = 1; off < 256; off <<= 1) {
        int t = (tid >= off) ? s[tid - off] : 0;
        __syncthreads();
        s[tid] += t;
        __syncthreads();
    }
    if (tid < SCAN_NBLK) bsum[tid] = (tid == 0) ? 0 : s[tid - 1];
    if (tid == 255) row_ptr[N_NODES] = s[255];
}

__global__ __launch_bounds__(256) void scan_apply(int* __restrict__ row_ptr,
                                                  const int* __restrict__ bsum,
                                                  int* __restrict__ cursor) {
    const int b   = blockIdx.x;
    const int off = bsum[b];
    const int i0  = b * SCAN_CHUNK + threadIdx.x * 4;
    if (i0 + 3 < N_NODES) {
        int4 v = *reinterpret_cast<int4*>(row_ptr + i0);
        v.x += off; v.y += off; v.z += off; v.w += off;
        *reinterpret_cast<int4*>(row_ptr + i0) = v;
        *reinterpret_cast<int4*>(cursor + i0)  = v;
    } else {
#pragma unroll
        for (int j = 0; j < 4; ++j) {
            if (i0 + j < N_NODES) {
                int t = row_ptr[i0 + j] + off;
                row_ptr[i0 + j] = t;
                cursor[i0 + j]  = t;
            }
        }
    }
}

// 4 edges per thread: int4/float4 coalesced reads, 4 independent
// atomic+store chains in flight per lane.
__global__ __launch_bounds__(256) void edge_scatter(
        const int* __restrict__ rows,
        const int* __restrict__ cols,
        const float* __restrict__ vals,
        int* __restrict__ cursor,
        float2* __restrict__ ecv) {
    int t = blockIdx.x * blockDim.x + threadIdx.x;
    int base = t * 4;
    if (base >= N_EDGES) return;   // N_EDGES % 4 == 0, quads never straddle
    int4   r4 = *reinterpret_cast<const int4*>(rows + base);
    int4   c4 = *reinterpret_cast<const int4*>(cols + base);
    float4 v4 = *reinterpret_cast<const float4*>(vals + base);

    int p0 = atomicAdd(&cursor[r4.x], 1);
    int p1 = atomicAdd(&cursor[r4.y], 1);
    int p2 = atomicAdd(&cursor[r4.z], 1);
    int p3 = atomicAdd(&cursor[r4.w], 1);
    float2 e0; e0.x = v4.x; e0.y = __int_as_float(c4.x); ecv[p0] = e0;
    float2 e1; e1.x = v4.y; e1.y = __int_as_float(c4.y); ecv[p1] = e1;
    float2 e2; e2.x = v4.z; e2.y = __int_as_float(c4.z); ecv[p2] = e2;
    float2 e3; e3.x = v4.w; e3.y = __int_as_float(c4.w); ecv[p3] = e3;
}

// ---------------------------------------------------------------------------
// CSR SpMM, one wave per row; quarter-wave per edge; fp16 gathers (8B/lane),
// fp32 accumulate. Fused: y16[row] = fp16(sum); acc[row] = (acc+sum)*scale.
// ---------------------------------------------------------------------------
__global__ __launch_bounds__(256) void spmm_csr(const int* __restrict__ row_ptr,
                                                const float2* __restrict__ ecv,
                                                const half4* __restrict__ x16,
                                                half4* __restrict__ y16,
                                                float* __restrict__ acc,
                                                float scale, int write_y) {
    int wave = (int)((blockIdx.x * blockDim.x + threadIdx.x) >> 6);
    int lane = threadIdx.x & 63;
    if (wave >= N_NODES) return;
    int row  = wave;
    int beg  = row_ptr[row];
    int end  = row_ptr[row + 1];
    int esub = lane >> 4;
    int p    = lane & 15;

    float4 a = make_float4(0.f, 0.f, 0.f, 0.f);
    for (int j = beg + esub; j < end; j += 4) {
        float2 cv = ecv[j];
        int c = __float_as_int(cv.y);
        half4 xv = x16[(size_t)c * 16 + p];
        a.x += cv.x * (float)xv.x;
        a.y += cv.x * (float)xv.y;
        a.z += cv.x * (float)xv.z;
        a.w += cv.x * (float)xv.w;
    }
#pragma unroll
    for (int m = 16; m <= 32; m <<= 1) {
        a.x += __shfl_xor(a.x, m, 64);
        a.y += __shfl_xor(a.y, m, 64);
        a.z += __shfl_xor(a.z, m, 64);
        a.w += __shfl_xor(a.w, m, 64);
    }
    if (esub == 0) {
        size_t idx = (size_t)row * 16 + p;
        if (write_y) {
            half4 h;
            h.x = (_Float16)a.x; h.y = (_Float16)a.y;
            h.z = (_Float16)a.z; h.w = (_Float16)a.w;
            y16[idx] = h;
        }
        float4 av = reinterpret_cast<float4*>(acc)[idx];
        av.x = (av.x + a.x) * scale;
        av.y = (av.y + a.y) * scale;
        av.z = (av.z + a.z) * scale;
        av.w = (av.w + a.w) * scale;
        reinterpret_cast<float4*>(acc)[idx] = av;
    }
}

extern "C" void kernel_launch(void* const* d_in, const int* in_sizes, int n_in,
                              void* d_out, int out_size, void* d_ws, size_t ws_size,
                              hipStream_t stream) {
    const float* user_emb   = (const float*)d_in[0];
    const float* item_emb   = (const float*)d_in[1];
    const float* cover_W    = (const float*)d_in[2];
    const float* item_cover = (const float*)d_in[3];
    const float* has_cover  = (const float*)d_in[4];
    const float* adj_vals   = (const float*)d_in[5];
    const int*   adj_rows   = (const int*)d_in[6];
    const int*   adj_cols   = (const int*)d_in[7];

    float* acc = (float*)d_out;  // [N_NODES][64] fp32

    const size_t feat16_bytes = (size_t)N_NODES * EMBED_DIM * 2;  // 19.2 MB

    char* base = (char*)d_ws;
    size_t off = 0;
    auto take = [&](size_t bytes) {
        char* p = base + off;
        off += (bytes + 255) & ~(size_t)255;
        return p;
    };
    half4*  x16     = (half4*)take(feat16_bytes);
    half4*  y16     = (half4*)take(feat16_bytes);
    float2* ecv     = (float2*)take((size_t)N_EDGES * sizeof(float2));
    int*    row_ptr = (int*)take((size_t)(N_NODES + 1) * sizeof(int));
    int*    cnt     = (int*)take((size_t)N_NODES * sizeof(int));
    int*    cursor  = (int*)take((size_t)N_NODES * sizeof(int));
    int*    bsum    = (int*)take((size_t)SCAN_NBLK * sizeof(int));
    (void)ws_size;  // ~72 MB needed; harness provides >=112 MB (proven R2-R4)

    // ---- x0 = concat(user_emb, item_emb + cover_proj); acc = x0 ----
    {
        int n4 = N_USERS * EMBED_DIM / 4;
        build_user_x<<<(n4 + 255) / 256, 256, 0, stream>>>(user_emb, x16, acc);
    }
    {
        int grid = (N_ITEMS + MT - 1) / MT;   // 391
        build_item_x_tiled<<<grid, 256, 0, stream>>>(
            item_emb, cover_W, item_cover, has_cover,
            x16 + (size_t)N_USERS * 16,
            acc + (size_t)N_USERS * EMBED_DIM);
    }

    // ---- CSR build (once; reused for all 3 layers) ----
    hipMemsetAsync(cnt, 0, (size_t)N_NODES * sizeof(int), stream);
    edge_count<<<(N_EDGES + 255) / 256, 256, 0, stream>>>(adj_rows, cnt);
    scan_local<<<SCAN_NBLK, 256, 0, stream>>>(cnt, row_ptr, bsum);
    scan_bsums<<<1, 256, 0, stream>>>(bsum, row_ptr);
    scan_apply<<<SCAN_NBLK, 256, 0, stream>>>(row_ptr, bsum, cursor);
    edge_scatter<<<(N_EDGES / 4 + 255) / 256, 256, 0, stream>>>(
        adj_rows, adj_cols, adj_vals, cursor, ecv);

    // ---- 3 propagation layers, acc update fused ----
    half4* x = x16;
    half4* y = y16;
    for (int l = 0; l < N_LAYERS; ++l) {
        bool last = (l == N_LAYERS - 1);
        int waves_per_block = 256 / 64;
        int grid = (N_NODES + waves_per_block - 1) / waves_per_block;
        spmm_csr<<<grid, 256, 0, stream>>>(
            row_ptr, ecv, x, y, acc,
            last ? 0.25f : 1.0f, last ? 0 : 1);
        half4* tmp = x; x = y; y = tmp;
    }
}